// Round 6
// baseline (1096.373 us; speedup 1.0000x reference)
//
#include <hip/hip_runtime.h>
#include <cmath>

#define NNODES 50000
#define NEDGES 800000
#define ORIG_FEA 92
#define NBR_FEA 41
#define HID 64
#define BN_EPS 1e-5f

typedef __attribute__((ext_vector_type(8))) short short8;
typedef __attribute__((ext_vector_type(4))) float f32x4;
typedef unsigned short ushort;
typedef unsigned int uint;

static __device__ __forceinline__ ushort f2bf(float f) {
    uint u = __float_as_uint(f);
    uint r = u + 0x7fffu + ((u >> 16) & 1u);   // round-to-nearest-even
    return (ushort)(r >> 16);
}

// ---------------------------------------------------------------------------
// prep: blocks 0..5 = (layer, f/s): pack B = [W_src(64); W2@We (41, pad 64)]
// (K=128) into MFMA B-fragment order Bpack[layer][t8][ck4][lane64][j8],
// k = ck*32+(lane>>4)*8+j, col = (t&3)*16+(lane&15). Also bcf/bcs biases.
// Block 6: zero 3 per-layer BN stats slots.
// ---------------------------------------------------------------------------
__global__ void prep(const float* __restrict__ W2, const float* __restrict__ b2,
                     const float* __restrict__ Wf, const float* __restrict__ bf,
                     const float* __restrict__ Ws, const float* __restrict__ bs,
                     ushort* __restrict__ Bpack, float* __restrict__ bcf,
                     float* __restrict__ bcs, float* __restrict__ stats) {
    if (blockIdx.x == 6) {
        for (int i = threadIdx.x; i < 3 * 128; i += blockDim.x) stats[i] = 0.f;
        return;
    }
    int layer = blockIdx.x >> 1;
    int fs = blockIdx.x & 1;
    const float* Wbig = (fs ? Ws : Wf) + layer * 192 * HID;
    const float* We = Wbig + 128 * HID;                 // e-part rows
    const float* bvec = (fs ? bs : bf) + layer * HID;
    float* bc = (fs ? bcs : bcf) + layer * HID;
    ushort* Bp = Bpack + layer * 16384 + fs * 8192;     // t = fs*4 + tt

    for (int idx = threadIdx.x; idx < 8192; idx += blockDim.x) {
        int j = idx & 7;
        int lane = (idx >> 3) & 63;
        int ck = (idx >> 9) & 3;
        int tt = (idx >> 11) & 3;
        int k = ck * 32 + ((lane >> 4) * 8) + j;
        int col = tt * 16 + (lane & 15);
        float v = 0.f;
        if (k < 64) v = Wbig[(64 + k) * HID + col];
        else if (k < 64 + NBR_FEA) {
            int r = k - 64;
            float a = 0.f;
            for (int m = 0; m < HID; ++m) a += W2[r * HID + m] * We[m * HID + col];
            v = a;
        }
        Bp[(tt * 4 + ck) * 512 + lane * 8 + j] = f2bf(v);
    }
    for (int c0 = threadIdx.x; c0 < HID; c0 += blockDim.x) {
        float a = bvec[c0];
        for (int m = 0; m < HID; ++m) a += b2[m] * We[m * HID + c0];
        bc[c0] = a;
    }
}

// ---------------------------------------------------------------------------
// CSR build: histogram -> scan -> scatter (gather-form for ea)
// ---------------------------------------------------------------------------
__global__ void k_hist(const int* __restrict__ eidx, int* __restrict__ deg) {
    int e = blockIdx.x * blockDim.x + threadIdx.x;
    if (e < NEDGES) atomicAdd(&deg[eidx[NEDGES + e]], 1);
}

__global__ void k_blocksum(const int* __restrict__ deg, int* __restrict__ bsum) {
    __shared__ int sh[256];
    int i = blockIdx.x * 256 + threadIdx.x;
    sh[threadIdx.x] = (i < NNODES) ? deg[i] : 0;
    __syncthreads();
    for (int s = 128; s > 0; s >>= 1) {
        if (threadIdx.x < s) sh[threadIdx.x] += sh[threadIdx.x + s];
        __syncthreads();
    }
    if (threadIdx.x == 0) bsum[blockIdx.x] = sh[0];
}

__global__ void k_scanbase(const int* __restrict__ bsum, int* __restrict__ bbase,
                           int* __restrict__ rowptr) {
    __shared__ int sh[256];
    int t = threadIdx.x;
    int v = (t < 196) ? bsum[t] : 0;
    sh[t] = v;
    __syncthreads();
    for (int s = 1; s < 256; s <<= 1) {
        int add = (t >= s) ? sh[t - s] : 0;
        __syncthreads();
        sh[t] += add;
        __syncthreads();
    }
    if (t < 196) bbase[t] = sh[t] - v;   // exclusive
    if (t == 0) rowptr[NNODES] = NEDGES;
}

__global__ void k_writerow(const int* __restrict__ deg, const int* __restrict__ bbase,
                           int* __restrict__ rowptr, int* __restrict__ cursor) {
    __shared__ int sh[256];
    int t = threadIdx.x;
    int i = blockIdx.x * 256 + t;
    int v = (i < NNODES) ? deg[i] : 0;
    sh[t] = v;
    __syncthreads();
    for (int s = 1; s < 256; s <<= 1) {
        int add = (t >= s) ? sh[t - s] : 0;
        __syncthreads();
        sh[t] += add;
        __syncthreads();
    }
    if (i < NNODES) {
        int e = bbase[blockIdx.x] + sh[t] - v;
        rowptr[i] = e;
        cursor[i] = e;
    }
}

__global__ void k_scatterA(const int* __restrict__ eidx, int* __restrict__ cursor,
                           int* __restrict__ eorig, int* __restrict__ srcs,
                           int* __restrict__ tgts) {
    int e = blockIdx.x * blockDim.x + threadIdx.x;
    if (e < NEDGES) {
        int tgt = eidx[NEDGES + e];
        int pos = atomicAdd(&cursor[tgt], 1);
        eorig[pos] = e;
        srcs[pos] = eidx[e];
        tgts[pos] = tgt;
    }
}

// gather-form: sequential write of sorted bf16 ea rows, random read of ea
__global__ void k_scatterB(const float* __restrict__ ea, const int* __restrict__ eorig,
                           ushort* __restrict__ eab_s) {
    long idx = (long)blockIdx.x * blockDim.x + threadIdx.x;
    if (idx >= (long)NEDGES * 8) return;
    int pos = (int)(idx >> 3);
    int j = (int)(idx & 7);
    int e = eorig[pos];
    uint w[4];
    #pragma unroll
    for (int m = 0; m < 4; ++m) {
        int k0 = j * 8 + m * 2, k1 = k0 + 1;
        uint u0 = (k0 < NBR_FEA) ? (uint)f2bf(ea[(long)e * NBR_FEA + k0]) : 0u;
        uint u1 = (k1 < NBR_FEA) ? (uint)f2bf(ea[(long)e * NBR_FEA + k1]) : 0u;
        w[m] = u0 | (u1 << 16);
    }
    uint4 o; o.x = w[0]; o.y = w[1]; o.z = w[2]; o.w = w[3];
    *(uint4*)(eab_s + (long)pos * 64 + j * 8) = o;
}

// ---------------------------------------------------------------------------
// Ttgt permuted layout: ch stored at (ch&15)*4+(ch>>4) (gate), +64 (softplus).
// embed + layer-0 target projection fused; also zeroes agg for edge layer 0.
// ---------------------------------------------------------------------------
__global__ void embed_proj(const float* __restrict__ x, const float* __restrict__ W1,
                           const float* __restrict__ b1,
                           const float* __restrict__ Wf, const float* __restrict__ Ws,
                           const float* __restrict__ bcf, const float* __restrict__ bcs,
                           float* __restrict__ h, ushort* __restrict__ h_bf,
                           float* __restrict__ Ttgt, float* __restrict__ agg) {
    __shared__ float Wl[2][HID][HID]; // 32 KB, layer-0 tgt blocks
    for (int idx = threadIdx.x; idx < HID * HID; idx += blockDim.x) {
        Wl[0][0][idx] = Wf[idx];   // rows 0..63 of layer 0
        Wl[1][0][idx] = Ws[idx];
    }
    __syncthreads();
    int lane = threadIdx.x & 63;
    int wid = (blockIdx.x * blockDim.x + threadIdx.x) >> 6;
    int nw = (gridDim.x * blockDim.x) >> 6;
    int pg = (lane & 15) * 4 + (lane >> 4);   // permuted position for channel=lane
    float bF = bcf[lane], bS = bcs[lane], b1v = b1[lane];
    for (int n = wid; n < NNODES; n += nw) {
        float acc = b1v;
        const float* xr = x + (long)n * ORIG_FEA;
        #pragma unroll 4
        for (int k = 0; k < ORIG_FEA; ++k) acc = fmaf(xr[k], W1[k * HID + lane], acc);
        h[n * HID + lane] = acc;
        h_bf[n * HID + lane] = f2bf(acc);
        agg[(long)n * HID + lane] = 0.f;
        float af = bF, as = bS;
        #pragma unroll 8
        for (int k = 0; k < HID; ++k) {
            float yk = __shfl(acc, k, 64);
            af = fmaf(yk, Wl[0][k][lane], af);
            as = fmaf(yk, Wl[1][k][lane], as);
        }
        Ttgt[(long)n * 128 + pg] = af;
        Ttgt[(long)n * 128 + 64 + pg] = as;
    }
}

// ---------------------------------------------------------------------------
// Edge kernel: UNIFORM 16-EDGE TILES over the sorted edge array.
// A = [h_bf[src] | eab_sorted] (K=128), 32 MFMA -> all 128 pre-act terms for
// 16 edges. Per-row Ttgt add (coalesced via permuted layout), activation,
// msg -> wave-private LDS [16 rows][64 ch, permuted]. Then lane=channel
// segmented-reduces the 16 rows by target (wave-uniform branches) and flushes
// each segment with ONE coalesced wave-atomic into agg. Perfect balance,
// no clamp waste, ~2 flushes/tile.
// ---------------------------------------------------------------------------
__global__ __launch_bounds__(256, 2) void edge_tile(
    const ushort* __restrict__ eab_s, const int* __restrict__ srcs,
    const int* __restrict__ tgts, const ushort* __restrict__ h_bf,
    const float* __restrict__ Ttgt, const ushort* __restrict__ Bpack,
    float* __restrict__ agg) {
    __shared__ float lds[4][16][64];   // 16 KB: per-wave 4 KB patch
    int lane = threadIdx.x & 63;
    int q = lane >> 4;
    int c = lane & 15;
    int p = c * 4 + q;                 // my channel's permuted LDS position
    float* myl = &lds[threadIdx.x >> 6][0][0];
    int wid = (blockIdx.x * blockDim.x + threadIdx.x) >> 6;
    int nw = (gridDim.x * blockDim.x) >> 6;

    short8 B[8][4];
    #pragma unroll
    for (int t = 0; t < 8; ++t)
        #pragma unroll
        for (int ck = 0; ck < 4; ++ck)
            B[t][ck] = *(const short8*)(Bpack + ((t * 4 + ck) * 512 + lane * 8));

    const int NT = NEDGES / 16;
    for (int tile = wid; tile < NT; tile += nw) {
        int e0 = tile * 16;
        int sv = srcs[e0 + c];
        const short8* hrow = (const short8*)(h_bf + (long)sv * 64);
        const short8* erow = (const short8*)(eab_s + (long)(e0 + c) * 64);
        short8 A0 = hrow[q], A1 = hrow[4 + q];
        short8 A2 = erow[q], A3 = erow[4 + q];

        f32x4 accf[4], accs[4];
        f32x4 z = {0.f, 0.f, 0.f, 0.f};
        #pragma unroll
        for (int t = 0; t < 4; ++t) {
            accf[t] = __builtin_amdgcn_mfma_f32_16x16x32_bf16(A0, B[t][0], z, 0, 0, 0);
            accs[t] = __builtin_amdgcn_mfma_f32_16x16x32_bf16(A0, B[t + 4][0], z, 0, 0, 0);
        }
        #pragma unroll
        for (int t = 0; t < 4; ++t) {
            accf[t] = __builtin_amdgcn_mfma_f32_16x16x32_bf16(A1, B[t][1], accf[t], 0, 0, 0);
            accs[t] = __builtin_amdgcn_mfma_f32_16x16x32_bf16(A1, B[t + 4][1], accs[t], 0, 0, 0);
        }
        #pragma unroll
        for (int t = 0; t < 4; ++t) {
            accf[t] = __builtin_amdgcn_mfma_f32_16x16x32_bf16(A2, B[t][2], accf[t], 0, 0, 0);
            accs[t] = __builtin_amdgcn_mfma_f32_16x16x32_bf16(A2, B[t + 4][2], accs[t], 0, 0, 0);
        }
        #pragma unroll
        for (int t = 0; t < 4; ++t) {
            accf[t] = __builtin_amdgcn_mfma_f32_16x16x32_bf16(A3, B[t][3], accf[t], 0, 0, 0);
            accs[t] = __builtin_amdgcn_mfma_f32_16x16x32_bf16(A3, B[t + 4][3], accs[t], 0, 0, 0);
        }

        // all 16 target ids (wave-uniform loads)
        int4 ta0 = *(const int4*)(tgts + e0);
        int4 ta1 = *(const int4*)(tgts + e0 + 4);
        int4 ta2 = *(const int4*)(tgts + e0 + 8);
        int4 ta3 = *(const int4*)(tgts + e0 + 12);
        int tall[16];
        tall[0] = ta0.x; tall[1] = ta0.y; tall[2] = ta0.z; tall[3] = ta0.w;
        tall[4] = ta1.x; tall[5] = ta1.y; tall[6] = ta1.z; tall[7] = ta1.w;
        tall[8] = ta2.x; tall[9] = ta2.y; tall[10] = ta2.z; tall[11] = ta2.w;
        tall[12] = ta3.x; tall[13] = ta3.y; tall[14] = ta3.z; tall[15] = ta3.w;

        // per-row messages -> LDS (row = q*4+r for this lane's quad)
        #pragma unroll
        for (int r = 0; r < 4; ++r) {
            int tgr = tall[4 * q + r];  // wait: rows of quad q are q*4+r
            const float* tp = Ttgt + (long)tgr * 128 + 4 * c;
            f32x4 tfv = *(const f32x4*)(tp);
            f32x4 tsv = *(const f32x4*)(tp + 64);
            f32x4 m;
            #pragma unroll
            for (int t = 0; t < 4; ++t) {
                float f = accf[t][r] + tfv[t];
                float s = accs[t][r] + tsv[t];
                float g = __builtin_amdgcn_rcpf(1.f + __expf(-f));
                float sp = fmaxf(s, 0.f) + __logf(1.f + __expf(-fabsf(s)));
                m[t] = g * sp;
            }
            *(f32x4*)(myl + (q * 4 + r) * 64 + c * 4) = m;
        }

        // segmented reduction: lane = channel, flush per target segment
        float acc = 0.f;
        int prev = tall[0];
        #pragma unroll
        for (int row = 0; row < 16; ++row) {
            int tr = tall[row];
            float v = myl[row * 64 + p];
            if (tr != prev) {
                atomicAdd(&agg[(long)prev * 64 + lane], acc);
                acc = 0.f;
                prev = tr;
            }
            acc += v;
        }
        atomicAdd(&agg[(long)prev * 64 + lane], acc);
    }
}

// ---------------------------------------------------------------------------
// BN stats: sum and sumsq per channel of (h + agg). stats pre-zeroed in prep.
// ---------------------------------------------------------------------------
__global__ void bn_stats(const float* __restrict__ h, const float* __restrict__ agg,
                         float* __restrict__ stats) {
    int lane = threadIdx.x & 63;
    int w = threadIdx.x >> 6;
    int gw = (blockIdx.x * blockDim.x + threadIdx.x) >> 6;
    int nw = (gridDim.x * blockDim.x) >> 6;
    float s = 0.f, sq = 0.f;
    for (int n = gw; n < NNODES; n += nw) {
        float v = h[n * HID + lane] + agg[n * HID + lane];
        s += v;
        sq = fmaf(v, v, sq);
    }
    __shared__ float ls[4][64], lq[4][64];
    ls[w][lane] = s; lq[w][lane] = sq;
    __syncthreads();
    if (threadIdx.x < 64) {
        float ts = ls[0][lane] + ls[1][lane] + ls[2][lane] + ls[3][lane];
        float tq = lq[0][lane] + lq[1][lane] + lq[2][lane] + lq[3][lane];
        atomicAdd(&stats[lane], ts);
        atomicAdd(&stats[64 + lane], tq);
    }
}

// ---------------------------------------------------------------------------
// BN apply (+ReLU) + NEXT layer's target projection; zeroes agg for the next
// edge pass. One wave/node.
// ---------------------------------------------------------------------------
__global__ __launch_bounds__(256) void bn_apply_proj(
    float* __restrict__ h, float* __restrict__ agg,
    const float* __restrict__ stats, const float* __restrict__ gamma,
    const float* __restrict__ beta, ushort* __restrict__ h_bf,
    const float* __restrict__ Wf, const float* __restrict__ Ws,
    const float* __restrict__ bcf, const float* __restrict__ bcs,
    float* __restrict__ Ttgt, int relu, int next_layer) {
    __shared__ float Wl[2][HID][HID]; // 32 KB
    if (next_layer >= 0) {
        const float* Wfb = Wf + (long)next_layer * 192 * HID;
        const float* Wsb = Ws + (long)next_layer * 192 * HID;
        for (int idx = threadIdx.x; idx < HID * HID; idx += blockDim.x) {
            Wl[0][0][idx] = Wfb[idx];
            Wl[1][0][idx] = Wsb[idx];
        }
        __syncthreads();
    }
    int lane = threadIdx.x & 63;
    int wid = (blockIdx.x * blockDim.x + threadIdx.x) >> 6;
    int nw = (gridDim.x * blockDim.x) >> 6;
    int pg = (lane & 15) * 4 + (lane >> 4);
    const float invn = 1.f / (float)NNODES;
    float mean = stats[lane] * invn;
    float var = stats[64 + lane] * invn - mean * mean;
    float rs = rsqrtf(var + BN_EPS);
    float ga = gamma[lane], be = beta[lane];
    float bF = 0.f, bS = 0.f;
    if (next_layer >= 0) {
        bF = bcf[next_layer * HID + lane];
        bS = bcs[next_layer * HID + lane];
    }
    for (int n = wid; n < NNODES; n += nw) {
        float v = h[n * HID + lane] + agg[n * HID + lane];
        float y = (v - mean) * rs * ga + be;
        if (relu) y = fmaxf(y, 0.f);
        h[n * HID + lane] = y;
        h_bf[n * HID + lane] = f2bf(y);
        if (next_layer >= 0) {
            agg[(long)n * HID + lane] = 0.f;    // pre-zero for next edge pass
            float af = bF, as = bS;
            #pragma unroll 8
            for (int k = 0; k < HID; ++k) {
                float yk = __shfl(y, k, 64);
                af = fmaf(yk, Wl[0][k][lane], af);
                as = fmaf(yk, Wl[1][k][lane], as);
            }
            Ttgt[(long)n * 128 + pg] = af;
            Ttgt[(long)n * 128 + 64 + pg] = as;
        }
    }
}

extern "C" void kernel_launch(void* const* d_in, const int* in_sizes, int n_in,
                              void* d_out, int out_size, void* d_ws, size_t ws_size,
                              hipStream_t stream) {
    const float* x    = (const float*)d_in[0];
    const float* ea   = (const float*)d_in[1];
    const int*   eidx = (const int*)d_in[2];
    const float* W1   = (const float*)d_in[3];
    const float* b1   = (const float*)d_in[4];
    const float* W2   = (const float*)d_in[5];
    const float* b2   = (const float*)d_in[6];
    const float* Wf   = (const float*)d_in[7];
    const float* bf   = (const float*)d_in[8];
    const float* Ws   = (const float*)d_in[9];
    const float* bs   = (const float*)d_in[10];
    const float* gamma= (const float*)d_in[11];
    const float* beta = (const float*)d_in[12];
    float* h = (float*)d_out; // [NNODES, 64]

    // workspace layout (256 B aligned sections)
    char* wb = (char*)d_ws;
    auto align = [&]() { wb = (char*)(((size_t)wb + 255) & ~(size_t)255); };
    ushort* Bpack = (ushort*)wb;  wb += 3 * 8 * 4 * 512 * sizeof(ushort); align(); // 96 KB
    float* bcf   = (float*)wb;    wb += 3 * HID * sizeof(float);
    float* bcs   = (float*)wb;    wb += 3 * HID * sizeof(float);
    float* stats = (float*)wb;    wb += 3 * 2 * HID * sizeof(float); align();
    int* deg     = (int*)wb;      wb += NNODES * sizeof(int);
    int* rowptr  = (int*)wb;      wb += (NNODES + 1) * sizeof(int);
    int* cursor  = (int*)wb;      wb += NNODES * sizeof(int);
    int* bsum    = (int*)wb;      wb += 256 * sizeof(int);
    int* bbase   = (int*)wb;      wb += 256 * sizeof(int); align();
    int* eorig   = (int*)wb;      wb += NEDGES * sizeof(int);          // 3.2 MB
    int* srcs    = (int*)wb;      wb += NEDGES * sizeof(int);          // 3.2 MB
    int* tgts    = (int*)wb;      wb += NEDGES * sizeof(int);          // 3.2 MB
    align();
    float* Ttgt  = (float*)wb;    wb += (size_t)NNODES * 128 * sizeof(float); // 25.6 MB
    float* agg   = (float*)wb;    wb += (size_t)NNODES * HID * sizeof(float); // 12.8 MB
    ushort* h_bf = (ushort*)wb;   wb += (size_t)NNODES * HID * sizeof(ushort); // 6.4 MB
    ushort* eab_s= (ushort*)wb;   wb += (size_t)NEDGES * 64 * sizeof(ushort);  // 102.4 MB

    // --- setup: weights+stats, CSR sort, embed+proj0(+agg zero) ---
    prep<<<7, 256, 0, stream>>>(W2, b2, Wf, bf, Ws, bs, Bpack, bcf, bcs, stats);

    hipMemsetAsync(deg, 0, NNODES * sizeof(int), stream);
    k_hist<<<(NEDGES + 255) / 256, 256, 0, stream>>>(eidx, deg);
    k_blocksum<<<196, 256, 0, stream>>>(deg, bsum);
    k_scanbase<<<1, 256, 0, stream>>>(bsum, bbase, rowptr);
    k_writerow<<<196, 256, 0, stream>>>(deg, bbase, rowptr, cursor);
    k_scatterA<<<(NEDGES + 255) / 256, 256, 0, stream>>>(eidx, cursor, eorig, srcs, tgts);
    k_scatterB<<<(NEDGES * 8 + 255) / 256, 256, 0, stream>>>(ea, eorig, eab_s);

    embed_proj<<<1024, 256, 0, stream>>>(x, W1, b1, Wf, Ws, bcf, bcs, h, h_bf, Ttgt, agg);

    for (int i = 0; i < 3; ++i) {
        edge_tile<<<2048, 256, 0, stream>>>(eab_s, srcs, tgts, h_bf, Ttgt,
                                            Bpack + i * 16384, agg);
        bn_stats<<<1024, 256, 0, stream>>>(h, agg, stats + i * 128);
        bn_apply_proj<<<1024, 256, 0, stream>>>(h, agg, stats + i * 128, gamma + i * HID,
                                                beta + i * HID, h_bf, Wf, Ws, bcf, bcs,
                                                Ttgt, (i < 2) ? 1 : 0,
                                                (i < 2) ? (i + 1) : -1);
    }
}